// Round 3
// baseline (498.795 us; speedup 1.0000x reference)
//
#include <hip/hip_runtime.h>
#include <hip/hip_bf16.h>
#include <stdint.h>

// Problem constants: M=512, P=256, B=128, T=1024
#define NB   128
#define NT   1024
#define NM   512
#define NP   256

typedef __attribute__((ext_vector_type(8))) short bf16x8;
typedef __attribute__((ext_vector_type(4))) float f32x4;
typedef unsigned int u32;

// pack two f32 -> two bf16 in one u32 (round-half-up; bias << bf16 ulp)
__device__ __forceinline__ uint32_t bfpair(float a, float b) {
    uint32_t ua = __float_as_uint(a) + 0x8000u;
    uint32_t ub = __float_as_uint(b) + 0x8000u;
    return __builtin_amdgcn_perm(ub, ua, 0x07060302u);
}

// RNE pack via HW: D.lo16 = bf16(lo), D.hi16 = bf16(hi)
__device__ __forceinline__ u32 cvtpk(float lo, float hi) {
    u32 d;
    asm("v_cvt_pk_bf16_f32 %0, %1, %2" : "=v"(d) : "v"(lo), "v"(hi));
    return d;
}

__device__ __forceinline__ float fast_tanh(float x) {
    float e = __expf(2.0f * x);                       // inf-safe
    return 1.0f - 2.0f * __builtin_amdgcn_rcpf(e + 1.0f);
}

// async global->LDS DMA, 16 B per lane; LDS dest = wave-uniform base + lane*16
typedef const __attribute__((address_space(1))) u32* gas_t;
typedef __attribute__((address_space(3))) u32* las_t;
__device__ __forceinline__ void dma16(const void* g, void* l) {
    __builtin_amdgcn_global_load_lds((gas_t)g, (las_t)l, 16, 0, 0);
}

// ---------- prep: 0..255 cvt U->bf16 | 256..383 wq GEMV | 384..511 zero d_out ----------
__global__ void prep_kernel(const float* __restrict__ U, unsigned short* __restrict__ Ub,
                            const float* __restrict__ d_t, const float* __restrict__ s_t,
                            const float* __restrict__ W, float* __restrict__ wq,
                            float* __restrict__ out) {
    const int bx = blockIdx.x;
    if (bx < 256) {
        int idx = bx * 256 + threadIdx.x;                  // 65536 threads, 1 float4 each
        float4 u = reinterpret_cast<const float4*>(U)[idx];
        reinterpret_cast<uint2*>(Ub)[idx] = make_uint2(bfpair(u.x, u.y), bfpair(u.z, u.w));
    } else if (bx < 384) {
        int g = (bx - 256) * 512 + threadIdx.x * 2;        // 2 outputs/thread -> 65536
        int b = g >> 9;
        const float* dt = d_t + (size_t)b * NP;
        const float* st = s_t + (size_t)b * NP;
        #pragma unroll
        for (int e = 0; e < 2; ++e) {
            int n = (g + e) & 511;
            const float* Wn = W + (size_t)n * 512;
            float s = 0.f;
            #pragma unroll 4
            for (int c = 0; c < NP; c += 4) {
                float4 w0 = *reinterpret_cast<const float4*>(Wn + c);
                float4 q0 = *reinterpret_cast<const float4*>(dt + c);
                s += w0.x * q0.x + w0.y * q0.y + w0.z * q0.z + w0.w * q0.w;
                float4 w1 = *reinterpret_cast<const float4*>(Wn + NP + c);
                float4 q1 = *reinterpret_cast<const float4*>(st + c);
                s += w1.x * q1.x + w1.y * q1.y + w1.z * q1.z + w1.w * q1.w;
            }
            wq[g + e] = s;
        }
    } else {
        int idx = (bx - 384) * 256 + threadIdx.x;          // 32768 float4 = 128K floats
        reinterpret_cast<float4*>(out)[idx] = make_float4(0.f, 0.f, 0.f, 0.f);
    }
}

// ---------- score v4: m201-style phased schedule ----------
// 512 threads = 8 waves (tw 0..1 x nw 0..3), block tile 128t x 256n, BK=64, 8 K-steps.
// LDS: As[2][128x64 bf16]=32KB dbuf (reg-staged A, fp32 H -> cvt_pk -> ds_write),
//      Bs[3][256x64 bf16]=96KB triple-buf (global_load_lds, chunk s+2 issued at step s).
// Total 128 KB -> 1 block/CU (2 waves/SIMD — m201 config).
// Per step: 2 phases (k-half). Phase = {ds_read 8xb128 [+ stage]} barrier lgkm0
//           setprio1 16xMFMA setprio0 barrier.  vmcnt(4) once per step (never 0).
// Swizzle (rows 128B = 8 slots of 16B): slot = chunk ^ (row&7); applied on A write,
// pre-swizzled B DMA source, and both frag reads (involution).
__global__ __launch_bounds__(512, 2)
void score_kernel(const float* __restrict__ H, const unsigned short* __restrict__ Ub,
                  const float* __restrict__ wq, const float* __restrict__ v_d,
                  float* __restrict__ out) {
    __shared__ __align__(16) unsigned char smem[131072];
    char* AsB = (char*)smem;              // 2 x 16384
    char* BsB = (char*)smem + 32768;      // 3 x 32768

    const int tid  = threadIdx.x;
    const int id   = blockIdx.x;
    const int tile = (id >> 4) * 8 + (id & 7);   // nh-pairs share XCD (id%8)
    const int nh   = (id >> 3) & 1;
    const int tt   = tile & 7;
    const int b    = tile >> 3;

    const int lane = tid & 63;
    const int w    = tid >> 6;          // 0..7
    const int lr   = lane & 15;
    const int lq   = lane >> 4;
    const int tw   = w >> 2;            // 0..1  t-half
    const int nw   = w & 3;             // 0..3  n-quarter

    // ---- A staging addresses: thread -> row rA = tid>>2, k-seg = tid&3 (16 floats) ----
    const int rA = tid >> 2, seg = tid & 3;
    const float* gA = H + ((size_t)(b * NT + tt * 128 + rA)) * NM + seg * 16;
    const u32 woff0 = (u32)(rA * 128 + (((2 * seg) ^ (rA & 7)) << 4));
    const u32 woff1 = woff0 ^ 16;       // chunk 2*seg+1

    // ---- B DMA: 4 instrs/thread, instr gi=w*4+q covers rows gi*8+(lane>>3) ----
    const unsigned short* gBq[4];
    u32 lBq[4];
    const u32 sOffB = (u32)(((lane & 7) ^ (lane >> 3)) * 8);   // pre-swizzled src chunk
    #pragma unroll
    for (int q = 0; q < 4; ++q) {
        int r = (w * 4 + q) * 8 + (lane >> 3);
        gBq[q] = Ub + (size_t)(nh * 256 + r) * NM + sOffB;
        lBq[q] = (u32)((w * 4 + q) * 1024 + lane * 16);
    }

    // ---- fragment read offsets: slot = (kh*4+lq) ^ (lr&7); kh toggles byte-bit 6 ----
    const u32 aoff = (u32)((tw * 64 + lr) * 128 + ((lq ^ (lr & 7)) << 4));
    const u32 boff = (u32)((nw * 64 + lr) * 128 + ((lq ^ (lr & 7)) << 4));

    f32x4 acc[4][4];
    #pragma unroll
    for (int i = 0; i < 4; ++i)
        #pragma unroll
        for (int j = 0; j < 4; ++j)
            acc[i][j] = (f32x4){0.f, 0.f, 0.f, 0.f};

    float4 av0[4], av1[4];
    // ---- prologue: Aload(0)->av0; Bdma(0)->Bs0; Bdma(1)->Bs1; write As0; Aload(1)->av1
    #pragma unroll
    for (int q = 0; q < 4; ++q) av0[q] = *reinterpret_cast<const float4*>(gA + q * 4);
    #pragma unroll
    for (int q = 0; q < 4; ++q) dma16(gBq[q], BsB + lBq[q]);
    #pragma unroll
    for (int q = 0; q < 4; ++q) dma16(gBq[q] + 64, BsB + 32768 + lBq[q]);
    {
        uint4 w0, w1;   // implicit vmcnt wait for av0 (oldest); Bdma stay in flight
        w0.x = cvtpk(av0[0].x, av0[0].y); w0.y = cvtpk(av0[0].z, av0[0].w);
        w0.z = cvtpk(av0[1].x, av0[1].y); w0.w = cvtpk(av0[1].z, av0[1].w);
        w1.x = cvtpk(av0[2].x, av0[2].y); w1.y = cvtpk(av0[2].z, av0[2].w);
        w1.z = cvtpk(av0[3].x, av0[3].y); w1.w = cvtpk(av0[3].z, av0[3].w);
        *reinterpret_cast<uint4*>(AsB + woff0) = w0;
        *reinterpret_cast<uint4*>(AsB + woff1) = w1;
    }
    #pragma unroll
    for (int q = 0; q < 4; ++q) av1[q] = *reinterpret_cast<const float4*>(gA + 64 + q * 4);
    asm volatile("s_waitcnt vmcnt(8)" ::: "memory");   // Bdma(0) landed; Bdma(1)+Aload(1) in flight
    asm volatile("s_waitcnt lgkmcnt(0)" ::: "memory");
    __builtin_amdgcn_s_barrier();
    __builtin_amdgcn_sched_barrier(0);

    // ---- 8 K-steps, fully unrolled; all buffer/reg indices compile-time ----
    #pragma unroll
    for (int s = 0; s < 8; ++s) {
        const char* ab = AsB + (s & 1) * 16384;
        const char* bb = BsB + (s % 3) * 32768;

        #pragma unroll
        for (int kh = 0; kh < 2; ++kh) {
            const u32 X = kh ? 64u : 0u;
            // phase reads: 8 x ds_read_b128
            bf16x8 a0 = *reinterpret_cast<const bf16x8*>(ab + (aoff ^ X));
            bf16x8 a1 = *reinterpret_cast<const bf16x8*>(ab + (aoff ^ X) + 2048);
            bf16x8 a2 = *reinterpret_cast<const bf16x8*>(ab + (aoff ^ X) + 4096);
            bf16x8 a3 = *reinterpret_cast<const bf16x8*>(ab + (aoff ^ X) + 6144);
            bf16x8 b0 = *reinterpret_cast<const bf16x8*>(bb + (boff ^ X));
            bf16x8 b1 = *reinterpret_cast<const bf16x8*>(bb + (boff ^ X) + 2048);
            bf16x8 b2 = *reinterpret_cast<const bf16x8*>(bb + (boff ^ X) + 4096);
            bf16x8 b3 = *reinterpret_cast<const bf16x8*>(bb + (boff ^ X) + 6144);

            if (kh == 0) {
                // stage: Bdma(s+2) -> Bs[(s+2)%3]
                if (s < 6) {
                    char* bwr = BsB + ((s + 2) % 3) * 32768;
                    #pragma unroll
                    for (int q = 0; q < 4; ++q)
                        dma16(gBq[q] + (size_t)(s + 2) * 64, bwr + lBq[q]);
                }
                // write A chunk s+1 (regs loaded at step s-1; auto vmcnt wait drains
                // everything older in-order, incl. Bdma(s+1))
                if (s < 7) {
                    float4 (&S)[4] = ((s + 1) & 1) ? av1 : av0;
                    char* an = AsB + ((s + 1) & 1) * 16384;
                    uint4 w0, w1;
                    w0.x = cvtpk(S[0].x, S[0].y); w0.y = cvtpk(S[0].z, S[0].w);
                    w0.z = cvtpk(S[1].x, S[1].y); w0.w = cvtpk(S[1].z, S[1].w);
                    w1.x = cvtpk(S[2].x, S[2].y); w1.y = cvtpk(S[2].z, S[2].w);
                    w1.z = cvtpk(S[3].x, S[3].y); w1.w = cvtpk(S[3].z, S[3].w);
                    *reinterpret_cast<uint4*>(an + woff0) = w0;
                    *reinterpret_cast<uint4*>(an + woff1) = w1;
                }
                // Aload chunk s+2 -> av[(s+2)&1]
                if (s < 6) {
                    float4 (&D)[4] = (s & 1) ? av1 : av0;
                    #pragma unroll
                    for (int q = 0; q < 4; ++q)
                        D[q] = *reinterpret_cast<const float4*>(gA + (size_t)(s + 2) * 64 + q * 4);
                }
            }

            __builtin_amdgcn_s_barrier();
            asm volatile("s_waitcnt lgkmcnt(0)" ::: "memory");
            __builtin_amdgcn_sched_barrier(0);
            __builtin_amdgcn_s_setprio(1);
            #pragma unroll
            for (int j = 0; j < 4; ++j) {
                bf16x8 bj = (j == 0) ? b0 : (j == 1) ? b1 : (j == 2) ? b2 : b3;
                acc[0][j] = __builtin_amdgcn_mfma_f32_16x16x32_bf16(a0, bj, acc[0][j], 0, 0, 0);
                acc[1][j] = __builtin_amdgcn_mfma_f32_16x16x32_bf16(a1, bj, acc[1][j], 0, 0, 0);
                acc[2][j] = __builtin_amdgcn_mfma_f32_16x16x32_bf16(a2, bj, acc[2][j], 0, 0, 0);
                acc[3][j] = __builtin_amdgcn_mfma_f32_16x16x32_bf16(a3, bj, acc[3][j], 0, 0, 0);
            }
            __builtin_amdgcn_s_setprio(0);
            if (kh == 1 && s < 6) {
                // counted drain, once per step, never 0: forces the 4 oldest of the
                // 8 ops issued this step done; keeps the 4 newest in flight.
                asm volatile("s_waitcnt vmcnt(4)" ::: "memory");
            }
            __builtin_amdgcn_s_barrier();
        }
    }

    // ---- epilogue: tanh + v-dot, LDS-transpose reduce (Bs region reused) ----
    // acc[i][j][r]: t = tt*128 + tw*64 + i*16 + lq*4 + r, n = nh*256 + nw*64 + j*16 + lr
    float* red = (float*)BsB;                    // [128][68] f32, stride 68 (bank-spread)
    const float* wqb = wq + (size_t)b * NM;
    float vv[4], wv[4];
    #pragma unroll
    for (int j = 0; j < 4; ++j) {
        int n = nh * 256 + nw * 64 + j * 16 + lr;
        vv[j] = v_d[n];
        wv[j] = wqb[n];
    }
    #pragma unroll
    for (int i = 0; i < 4; ++i) {
        #pragma unroll
        for (int r = 0; r < 4; ++r) {
            float s = 0.f;
            #pragma unroll
            for (int j = 0; j < 4; ++j)
                s += vv[j] * fast_tanh(wv[j] + acc[i][j][r]);
            red[(tw * 64 + i * 16 + lq * 4 + r) * 68 + nw * 16 + lr] = s;
        }
    }
    __syncthreads();
    {
        const int t = tid >> 2, q = tid & 3;
        const float* rp = red + (size_t)t * 68 + q * 16;
        float4 x0 = *reinterpret_cast<const float4*>(rp);
        float4 x1 = *reinterpret_cast<const float4*>(rp + 4);
        float4 x2 = *reinterpret_cast<const float4*>(rp + 8);
        float4 x3 = *reinterpret_cast<const float4*>(rp + 12);
        float s = (x0.x + x0.y + x0.z + x0.w) + (x1.x + x1.y + x1.z + x1.w)
                + (x2.x + x2.y + x2.z + x2.w) + (x3.x + x3.y + x3.z + x3.w);
        s += __shfl_xor(s, 1, 64);
        s += __shfl_xor(s, 2, 64);
        if (q == 0) atomicAdd(&out[(size_t)b * NT + tt * 128 + t], s);
    }
}

// ---------- softmax over T=1024, in place, one WG per b ----------
__global__ void softmax_kernel(float* __restrict__ out) {
    const int b   = blockIdx.x;
    const int tid = threadIdx.x;          // 256 threads x 4 elems
    float* p = out + (size_t)b * NT;
    float4 v = reinterpret_cast<float4*>(p)[tid];
    float m = fmaxf(fmaxf(v.x, v.y), fmaxf(v.z, v.w));
    #pragma unroll
    for (int off = 32; off >= 1; off >>= 1)
        m = fmaxf(m, __shfl_xor(m, off, 64));
    __shared__ float red[8];
    const int wv = tid >> 6;
    if ((tid & 63) == 0) red[wv] = m;
    __syncthreads();
    m = fmaxf(fmaxf(red[0], red[1]), fmaxf(red[2], red[3]));
    float e0 = __expf(v.x - m), e1 = __expf(v.y - m);
    float e2 = __expf(v.z - m), e3 = __expf(v.w - m);
    float s = e0 + e1 + e2 + e3;
    #pragma unroll
    for (int off = 32; off >= 1; off >>= 1)
        s += __shfl_xor(s, off, 64);
    if ((tid & 63) == 0) red[4 + wv] = s;
    __syncthreads();
    s = red[4] + red[5] + red[6] + red[7];
    float inv = 1.f / s;
    float4 o;
    o.x = e0 * inv; o.y = e1 * inv; o.z = e2 * inv; o.w = e3 * inv;
    reinterpret_cast<float4*>(p)[tid] = o;
}

extern "C" void kernel_launch(void* const* d_in, const int* in_sizes, int n_in,
                              void* d_out, int out_size, void* d_ws, size_t ws_size,
                              hipStream_t stream) {
    const float* d_t = (const float*)d_in[0];
    const float* s_t = (const float*)d_in[1];
    const float* H   = (const float*)d_in[2];
    // d_in[3] = T (scalar, 1024) — shapes hard-coded
    const float* W_d = (const float*)d_in[4];
    const float* U_d = (const float*)d_in[5];
    const float* v_d = (const float*)d_in[6];
    float* out = (float*)d_out;

    unsigned short* Ub = (unsigned short*)d_ws;              // 512 KB bf16 U
    float* wq = (float*)((char*)d_ws + 512 * 1024);          // 256 KB fp32 wq

    prep_kernel<<<512, 256, 0, stream>>>(U_d, Ub, d_t, s_t, W_d, wq, out);
    score_kernel<<<2048, 512, 0, stream>>>(H, Ub, wq, v_d, out);
    softmax_kernel<<<NB, 256, 0, stream>>>(out);
}

// Round 4
// 474.159 us; speedup vs baseline: 1.0520x; 1.0520x over previous
//
#include <hip/hip_runtime.h>
#include <hip/hip_bf16.h>
#include <stdint.h>

// Problem constants: M=512, P=256, B=128, T=1024
#define NB   128
#define NT   1024
#define NM   512
#define NP   256

typedef __attribute__((ext_vector_type(8))) short bf16x8;
typedef __attribute__((ext_vector_type(4))) float f32x4;
typedef unsigned int u32;

// pack two f32 -> two bf16 in one u32 (round-half-up; bias << bf16 ulp)
__device__ __forceinline__ uint32_t bfpair(float a, float b) {
    uint32_t ua = __float_as_uint(a) + 0x8000u;
    uint32_t ub = __float_as_uint(b) + 0x8000u;
    return __builtin_amdgcn_perm(ub, ua, 0x07060302u);
}

// RNE pack via HW: D.lo16 = bf16(lo), D.hi16 = bf16(hi)
__device__ __forceinline__ u32 cvtpk(float lo, float hi) {
    u32 d;
    asm("v_cvt_pk_bf16_f32 %0, %1, %2" : "=v"(d) : "v"(lo), "v"(hi));
    return d;
}

__device__ __forceinline__ float fast_tanh(float x) {
    float e = __expf(2.0f * x);                       // inf-safe
    return 1.0f - 2.0f * __builtin_amdgcn_rcpf(e + 1.0f);
}

// ---------- prep: 0..255 cvt U->bf16 | 256..383 wq GEMV | 384..511 zero d_out ----------
__global__ void prep_kernel(const float* __restrict__ U, unsigned short* __restrict__ Ub,
                            const float* __restrict__ d_t, const float* __restrict__ s_t,
                            const float* __restrict__ W, float* __restrict__ wq,
                            float* __restrict__ out) {
    const int bx = blockIdx.x;
    if (bx < 256) {
        int idx = bx * 256 + threadIdx.x;                  // 65536 threads, 1 float4 each
        float4 u = reinterpret_cast<const float4*>(U)[idx];
        reinterpret_cast<uint2*>(Ub)[idx] = make_uint2(bfpair(u.x, u.y), bfpair(u.z, u.w));
    } else if (bx < 384) {
        int g = (bx - 256) * 512 + threadIdx.x * 2;        // 2 outputs/thread -> 65536
        int b = g >> 9;
        const float* dt = d_t + (size_t)b * NP;
        const float* st = s_t + (size_t)b * NP;
        #pragma unroll
        for (int e = 0; e < 2; ++e) {
            int n = (g + e) & 511;
            const float* Wn = W + (size_t)n * 512;
            float s = 0.f;
            #pragma unroll 4
            for (int c = 0; c < NP; c += 4) {
                float4 w0 = *reinterpret_cast<const float4*>(Wn + c);
                float4 q0 = *reinterpret_cast<const float4*>(dt + c);
                s += w0.x * q0.x + w0.y * q0.y + w0.z * q0.z + w0.w * q0.w;
                float4 w1 = *reinterpret_cast<const float4*>(Wn + NP + c);
                float4 q1 = *reinterpret_cast<const float4*>(st + c);
                s += w1.x * q1.x + w1.y * q1.y + w1.z * q1.z + w1.w * q1.w;
            }
            wq[g + e] = s;
        }
    } else {
        int idx = (bx - 384) * 256 + threadIdx.x;          // 32768 float4 = 128K floats
        reinterpret_cast<float4*>(out)[idx] = make_float4(0.f, 0.f, 0.f, 0.f);
    }
}

// ---------- score v5: B-in-registers, A-streaming, 128-step hot loop ----------
// Grid 256 = (b 0..127) x (nh 0..1), 1 block/CU exactly (no rounds, no tail).
// XCD pairing: b = (id&7) + 8*(id>>4), nh = (id>>3)&1 -> nh-pair ids differ by 8
// => same XCD => H rows shared in that XCD's L2.
// 512 threads = 8 waves; wave w owns n-cols [nh*256 + w*32, +32).
// B-panel (U^T slice) lives in REGISTERS: Bf[2 nf][16 kf] bf16x8 = 128 VGPR,
// loaded once from Ub (bf16, L2-hot). Zero B traffic in the hot loop.
// Hot loop: 16 t-tiles x 8 K-steps (K-step 64) = 128 steps. Per step per wave:
//   8 ds_read_b128 (A frags, all waves share the 64-row tile) -> 16 MFMA
//   + Aload(S+2)->regs (2 float4) + cvt_pk + 1 ds_write_b128 (chunk S+1, alt buf)
//   + lgkmcnt(0) + s_barrier  (NO vmcnt drain -- A loads fly across barriers)
// As: 2 x [64 rows x 128 B] bf16, slot = seg ^ (row&7) XOR-swizzle (2-way max).
// Per-tile epilogue: tanh + v-dot, lr-shfl reduce, LDS transpose, atomicAdd.
__global__ __launch_bounds__(512, 2)
void score_kernel(const float* __restrict__ H, const unsigned short* __restrict__ Ub,
                  const float* __restrict__ wq, const float* __restrict__ v_d,
                  float* __restrict__ out) {
    __shared__ __align__(16) unsigned char smem[16384 + 64 * 9 * 4];
    char* AsB = (char*)smem;                    // 2 x 8192
    float* redf = (float*)(smem + 16384);       // [64][9]

    const int tid  = threadIdx.x;
    const int id   = blockIdx.x;
    const int b    = (id & 7) + ((id >> 4) << 3);
    const int nh   = (id >> 3) & 1;

    const int lane = tid & 63;
    const int w    = tid >> 6;          // 0..7 : n-group
    const int lr   = lane & 15;
    const int lq   = lane >> 4;

    // ---- B panel -> registers: Bf[nf][kf], lane holds Ub[n][k..k+8] ----
    bf16x8 Bf[2][16];
    {
        const unsigned short* gb = Ub + (size_t)(nh * 256 + w * 32 + lr) * NM + lq * 8;
        #pragma unroll
        for (int nf = 0; nf < 2; ++nf)
            #pragma unroll
            for (int kf = 0; kf < 16; ++kf)
                Bf[nf][kf] = *reinterpret_cast<const bf16x8*>(gb + nf * 16 * NM + kf * 32);
    }

    // ---- per-thread A staging: row = tid>>3 (0..63), seg = tid&7 (8 k-floats) ----
    const int rowA = tid >> 3, seg = tid & 7;
    const float* gAt = H + (size_t)b * NT * NM + (size_t)rowA * NM + seg * 8;  // tile 0
    const u32 woff = (u32)(rowA * 128 + ((seg ^ (rowA & 7)) << 4));

    // frag read base: row = 16tf + lr, granule (kf*4+lq), slot = granule^(row&7)
    const u32 aoB = (u32)(lr * 128 + ((lq ^ (lr & 7)) << 4));

    // epilogue constants
    float vv[2], wvq[2];
    {
        const int nb0 = nh * 256 + w * 32 + lr;
        vv[0]  = v_d[nb0];            vv[1]  = v_d[nb0 + 16];
        wvq[0] = wq[b * NM + nb0];    wvq[1] = wq[b * NM + nb0 + 16];
    }

    f32x4 acc[4][2];
    #pragma unroll
    for (int i = 0; i < 4; ++i) { acc[i][0] = (f32x4){0,0,0,0}; acc[i][1] = (f32x4){0,0,0,0}; }

    // ---- A prologue: chunk0 -> av[0], chunk1 -> av[1]; write chunk0 -> As[0] ----
    float4 av[2][2];
    av[0][0] = *reinterpret_cast<const float4*>(gAt);
    av[0][1] = *reinterpret_cast<const float4*>(gAt + 4);
    av[1][0] = *reinterpret_cast<const float4*>(gAt + 64);
    av[1][1] = *reinterpret_cast<const float4*>(gAt + 64 + 4);
    {
        uint4 wv4;   // implicit vmcnt wait (drains B + av[0]; one-time cost)
        wv4.x = cvtpk(av[0][0].x, av[0][0].y); wv4.y = cvtpk(av[0][0].z, av[0][0].w);
        wv4.z = cvtpk(av[0][1].x, av[0][1].y); wv4.w = cvtpk(av[0][1].z, av[0][1].w);
        *reinterpret_cast<uint4*>(AsB + woff) = wv4;
    }
    asm volatile("s_waitcnt lgkmcnt(0)" ::: "memory");
    __builtin_amdgcn_s_barrier();
    __builtin_amdgcn_sched_barrier(0);

    float* outb = out + (size_t)b * NT;

    #pragma unroll 1
    for (int tt = 0; tt < 16; ++tt) {
        const float* gAtn = (tt < 15) ? (gAt + 64 * NM) : gAt;   // clamped tail

        #pragma unroll
        for (int s = 0; s < 8; ++s) {
            const char* rb = AsB + (s & 1) * 8192;

            // A fragments for this K-step (8 x ds_read_b128, swizzled)
            bf16x8 a[4][2];
            #pragma unroll
            for (int tf = 0; tf < 4; ++tf)
                #pragma unroll
                for (int kf = 0; kf < 2; ++kf)
                    a[tf][kf] = *reinterpret_cast<const bf16x8*>(
                        rb + ((aoB ^ (u32)(kf << 6)) + tf * 2048));

            // issue-early: global load of chunk S+2 -> av[s&1]
            {
                const float* ga = (s < 6) ? (gAt + (s + 2) * 64)
                                          : (gAtn + (s - 6) * 64);
                av[s & 1][0] = *reinterpret_cast<const float4*>(ga);
                av[s & 1][1] = *reinterpret_cast<const float4*>(ga + 4);
            }

            // 16 MFMA (B from registers; compiler auto lgkm-waits for frags)
            #pragma unroll
            for (int tf = 0; tf < 4; ++tf)
                #pragma unroll
                for (int nf = 0; nf < 2; ++nf)
                    #pragma unroll
                    for (int kf = 0; kf < 2; ++kf)
                        acc[tf][nf] = __builtin_amdgcn_mfma_f32_16x16x32_bf16(
                            a[tf][kf], Bf[nf][(s & 7) * 2 + kf], acc[tf][nf], 0, 0, 0);

            // write-late: chunk S+1 (regs loaded last step; compiler auto vmcnt(2))
            {
                float4 A0 = av[(s + 1) & 1][0], A1 = av[(s + 1) & 1][1];
                uint4 wv4;
                wv4.x = cvtpk(A0.x, A0.y); wv4.y = cvtpk(A0.z, A0.w);
                wv4.z = cvtpk(A1.x, A1.y); wv4.w = cvtpk(A1.z, A1.w);
                *reinterpret_cast<uint4*>(AsB + (((s + 1) & 1) * 8192) + woff) = wv4;
            }

            // barrier with lgkm-only drain: A global loads STAY IN FLIGHT
            asm volatile("s_waitcnt lgkmcnt(0)" ::: "memory");
            __builtin_amdgcn_s_barrier();
            __builtin_amdgcn_sched_barrier(0);
        }

        // ---- per-tile epilogue: t = tt*64 + 16tf + lq*4 + r, n = nh*256+w*32+16nf+lr
        #pragma unroll
        for (int tf = 0; tf < 4; ++tf) {
            #pragma unroll
            for (int r = 0; r < 4; ++r) {
                float sv = vv[0] * fast_tanh(wvq[0] + acc[tf][0][r])
                         + vv[1] * fast_tanh(wvq[1] + acc[tf][1][r]);
                sv += __shfl_xor(sv, 1, 64);
                sv += __shfl_xor(sv, 2, 64);
                sv += __shfl_xor(sv, 4, 64);
                sv += __shfl_xor(sv, 8, 64);
                if (lr == 0) redf[(tf * 16 + lq * 4 + r) * 9 + w] = sv;
            }
            acc[tf][0] = (f32x4){0, 0, 0, 0};
            acc[tf][1] = (f32x4){0, 0, 0, 0};
        }
        asm volatile("s_waitcnt lgkmcnt(0)" ::: "memory");
        __builtin_amdgcn_s_barrier();
        __builtin_amdgcn_sched_barrier(0);
        if (tid < 64) {
            const float* rp = redf + tid * 9;
            float s = ((rp[0] + rp[1]) + (rp[2] + rp[3]))
                    + ((rp[4] + rp[5]) + (rp[6] + rp[7]));
            atomicAdd(&outb[tt * 64 + tid], s);
        }
        gAt += 64 * NM;
        // no extra barrier: redf readers finish before next epilogue's writes
        // (8 step-barriers in between order them)
    }
}

// ---------- softmax over T=1024, in place, one WG per b ----------
__global__ void softmax_kernel(float* __restrict__ out) {
    const int b   = blockIdx.x;
    const int tid = threadIdx.x;          // 256 threads x 4 elems
    float* p = out + (size_t)b * NT;
    float4 v = reinterpret_cast<float4*>(p)[tid];
    float m = fmaxf(fmaxf(v.x, v.y), fmaxf(v.z, v.w));
    #pragma unroll
    for (int off = 32; off >= 1; off >>= 1)
        m = fmaxf(m, __shfl_xor(m, off, 64));
    __shared__ float red[8];
    const int wv = tid >> 6;
    if ((tid & 63) == 0) red[wv] = m;
    __syncthreads();
    m = fmaxf(fmaxf(red[0], red[1]), fmaxf(red[2], red[3]));
    float e0 = __expf(v.x - m), e1 = __expf(v.y - m);
    float e2 = __expf(v.z - m), e3 = __expf(v.w - m);
    float s = e0 + e1 + e2 + e3;
    #pragma unroll
    for (int off = 32; off >= 1; off >>= 1)
        s += __shfl_xor(s, off, 64);
    if ((tid & 63) == 0) red[4 + wv] = s;
    __syncthreads();
    s = red[4] + red[5] + red[6] + red[7];
    float inv = 1.f / s;
    float4 o;
    o.x = e0 * inv; o.y = e1 * inv; o.z = e2 * inv; o.w = e3 * inv;
    reinterpret_cast<float4*>(p)[tid] = o;
}

extern "C" void kernel_launch(void* const* d_in, const int* in_sizes, int n_in,
                              void* d_out, int out_size, void* d_ws, size_t ws_size,
                              hipStream_t stream) {
    const float* d_t = (const float*)d_in[0];
    const float* s_t = (const float*)d_in[1];
    const float* H   = (const float*)d_in[2];
    // d_in[3] = T (scalar, 1024) — shapes hard-coded
    const float* W_d = (const float*)d_in[4];
    const float* U_d = (const float*)d_in[5];
    const float* v_d = (const float*)d_in[6];
    float* out = (float*)d_out;

    unsigned short* Ub = (unsigned short*)d_ws;              // 512 KB bf16 U
    float* wq = (float*)((char*)d_ws + 512 * 1024);          // 256 KB fp32 wq

    prep_kernel<<<512, 256, 0, stream>>>(U_d, Ub, d_t, s_t, W_d, wq, out);
    score_kernel<<<256, 512, 0, stream>>>(H, Ub, wq, v_d, out);
    softmax_kernel<<<NB, 256, 0, stream>>>(out);
}